// Round 3
// baseline (526.926 us; speedup 1.0000x reference)
//
#include <hip/hip_runtime.h>
#include <cstdint>

constexpr int H  = 16;
constexpr int D  = 64;
constexpr int DM = 1024;
constexpr int B  = 2;
constexpr int SL = 1024;
constexpr int CL = 512;
constexpr int KL = SL + CL;   // 1536
constexpr int EPAD = 1540;    // bf16 e-row stride (shorts); 770 words % 32 = 2
constexpr size_t M1 = 1u << 20;

typedef short bf16x8  __attribute__((ext_vector_type(8)));
typedef float f32x4   __attribute__((ext_vector_type(4)));
typedef short short4v __attribute__((ext_vector_type(4)));

__device__ __forceinline__ short f2b(float f) {
    uint32_t u = __float_as_uint(f);
    u = (u + 0x7fffu + ((u >> 16) & 1u)) >> 16;   // RNE fp32 -> bf16
    return (short)u;
}

__device__ __forceinline__ bf16x8 ld8(const unsigned short* p) {
    return *reinterpret_cast<const bf16x8*>(p);
}

__device__ __forceinline__ void async16(const void* g, void* l) {
    __builtin_amdgcn_global_load_lds(
        (const __attribute__((address_space(1))) void*)g,
        (__attribute__((address_space(3))) void*)l,
        16, 0, 0);
}

// ---------------- fp32 -> bf16 bulk convert --------------------------------
struct ConvSrc { const float* p[8]; };

__global__ __launch_bounds__(256)
void convert_kernel(ConvSrc srcs, unsigned short* __restrict__ dst)
{
    size_t i8 = (size_t)blockIdx.x * 256 + threadIdx.x;
    size_t e  = i8 * 8;                                   // < 9M
    int u = (int)(e >> 20);
    const float* s; size_t off;
    if (u < 2) { s = srcs.p[0]; off = e; }
    else       { s = srcs.p[u - 1]; off = e - ((size_t)u << 20); }
    float4 a = *reinterpret_cast<const float4*>(s + off);
    float4 b = *reinterpret_cast<const float4*>(s + off + 4);
    bf16x8 r;
    r[0]=f2b(a.x); r[1]=f2b(a.y); r[2]=f2b(a.z); r[3]=f2b(a.w);
    r[4]=f2b(b.x); r[5]=f2b(b.y); r[6]=f2b(b.z); r[7]=f2b(b.w);
    *reinterpret_cast<bf16x8*>(dst + e) = r;
}

// ---------------- 64x128-tile, BK=64, swizzled-LDS bf16 GEMM ---------------
// C[M,1024] = A[M,1024] @ W[1024,1024]^T + bias, scaled.
// LDS chunk map: chunk(row,g) = row*8 + (g ^ (row&7)); 16B chunks.
// MODE 0: bf16 -> [b, h, OUTLEN, 64] at row offset ROWOFF
// MODE 1: bf16 V^T -> [b, h, 64, KL] at col offset ROWOFF
// MODE 2: fp32 row-major [M, 1024] (nontemporal)
template<int MODE, int RPB_SHIFT, int OUTLEN, int ROWOFF>
__device__ __forceinline__ void gemm_body(
    const unsigned short* __restrict__ A,
    const unsigned short* __restrict__ W,
    const float* __restrict__ bias,
    void* __restrict__ outp, float scale,
    unsigned short* sA, unsigned short* sB, int by, int bx)
{
    const int t   = threadIdx.x;
    const int l   = t & 63;
    const int wid = t >> 6;         // 0..3, owns 32 output cols
    const int lr  = l & 15, lg = l >> 4;
    const int mbase = by * 64;
    const int nbase = bx * 128;

    f32x4 acc[4][2] = {};
    for (int k0 = 0; k0 < DM; k0 += 64) {
        // stage A: 512 chunks (2/thread), B: 1024 chunks (4/thread)
        #pragma unroll
        for (int i = 0; i < 2; ++i) {
            int c = t + 256 * i;
            int row = c >> 3, gd = (c & 7) ^ (row & 7);
            async16(A + (size_t)(mbase + row) * DM + k0 + gd * 8, sA + c * 8);
        }
        #pragma unroll
        for (int i = 0; i < 4; ++i) {
            int c = t + 256 * i;
            int row = c >> 3, gd = (c & 7) ^ (row & 7);
            async16(W + (size_t)(nbase + row) * DM + k0 + gd * 8, sB + c * 8);
        }
        __syncthreads();
        bf16x8 af[4][2], bfr[2][2];
        #pragma unroll
        for (int s = 0; s < 2; ++s) {
            #pragma unroll
            for (int i = 0; i < 4; ++i) {
                int row = i * 16 + lr;
                af[i][s] = ld8(sA + (row * 8 + ((s * 4 + lg) ^ (row & 7))) * 8);
            }
            #pragma unroll
            for (int j = 0; j < 2; ++j) {
                int row = wid * 32 + j * 16 + lr;
                bfr[j][s] = ld8(sB + (row * 8 + ((s * 4 + lg) ^ (row & 7))) * 8);
            }
        }
        #pragma unroll
        for (int s = 0; s < 2; ++s)
            #pragma unroll
            for (int i = 0; i < 4; ++i)
                #pragma unroll
                for (int j = 0; j < 2; ++j)
                    acc[i][j] = __builtin_amdgcn_mfma_f32_16x16x32_bf16(af[i][s], bfr[j][s], acc[i][j], 0, 0, 0);
        __syncthreads();
    }

    #pragma unroll
    for (int mi = 0; mi < 4; ++mi) {
        #pragma unroll
        for (int nj = 0; nj < 2; ++nj) {
            int n = nbase + wid * 32 + nj * 16 + lr;     // C/D col = lane&15
            float bi = bias[n];
            if (MODE == 1) {
                int m0 = mbase + mi * 16 + lg * 4;
                int bb = m0 >> RPB_SHIFT;
                int s0 = m0 & ((1 << RPB_SHIFT) - 1);
                int hh = n >> 6, dd = n & 63;
                unsigned short* o = (unsigned short*)outp +
                    ((size_t)(bb * H + hh) * D + dd) * KL + ROWOFF + s0;
                short4v pk;
                #pragma unroll
                for (int r = 0; r < 4; ++r) pk[r] = f2b((acc[mi][nj][r] + bi) * scale);
                *reinterpret_cast<short4v*>(o) = pk;
            } else {
                #pragma unroll
                for (int r = 0; r < 4; ++r) {
                    int m = mbase + mi * 16 + lg * 4 + r;
                    float v = (acc[mi][nj][r] + bi) * scale;
                    if (MODE == 0) {
                        int bb = m >> RPB_SHIFT;
                        int s  = m & ((1 << RPB_SHIFT) - 1);
                        int hh = n >> 6, dd = n & 63;
                        ((unsigned short*)outp)[((size_t)(bb * H + hh) * OUTLEN + ROWOFF + s) * D + dd]
                            = (unsigned short)f2b(v);
                    } else {
                        __builtin_nontemporal_store(v, (float*)outp + (size_t)m * DM + n);
                    }
                }
            }
        }
    }
}

// all 5 projections in one launch: 1024 blocks
__global__ __launch_bounds__(256)
void proj_kernel(const unsigned short* __restrict__ Aself,
                 const unsigned short* __restrict__ Actx,
                 const unsigned short* __restrict__ Wq,
                 const unsigned short* __restrict__ Wks,
                 const unsigned short* __restrict__ Wvs,
                 const unsigned short* __restrict__ Wkc,
                 const unsigned short* __restrict__ Wvc,
                 const float* __restrict__ bq,  const float* __restrict__ bks,
                 const float* __restrict__ bvs, const float* __restrict__ bkc,
                 const float* __restrict__ bvc,
                 unsigned short* __restrict__ q_ws,
                 unsigned short* __restrict__ k_ws,
                 unsigned short* __restrict__ vT_ws)
{
    __shared__ unsigned short sA[64 * 64];    // 8 KB
    __shared__ unsigned short sB[128 * 64];   // 16 KB
    int bid = blockIdx.x;
    int z, by, bx;
    if (bid < 768) { z = bid >> 8; int r = bid & 255; by = r >> 3; bx = r & 7; }
    else { int tt = bid - 768; z = 3 + (tt >> 7); int r = tt & 127; by = r >> 3; bx = r & 7; }
    if (z == 0)
        gemm_body<0, 10, SL, 0 >(Aself, Wq,  bq,  q_ws,  0.125f, sA, sB, by, bx);
    else if (z == 1)
        gemm_body<0, 10, KL, 0 >(Aself, Wks, bks, k_ws,  1.0f,   sA, sB, by, bx);
    else if (z == 2)
        gemm_body<1, 10, 0,  0 >(Aself, Wvs, bvs, vT_ws, 1.0f,   sA, sB, by, bx);
    else if (z == 3)
        gemm_body<0, 9,  KL, SL>(Actx,  Wkc, bkc, k_ws,  1.0f,   sA, sB, by, bx);
    else
        gemm_body<1, 9,  0,  SL>(Actx,  Wvc, bvc, vT_ws, 1.0f,   sA, sB, by, bx);
}

__global__ __launch_bounds__(256)
void out_proj_kernel(const unsigned short* __restrict__ ctx_bf,
                     const unsigned short* __restrict__ Wo,
                     const float* __restrict__ bo,
                     float* __restrict__ out0)
{
    __shared__ unsigned short sA[64 * 64];
    __shared__ unsigned short sB[128 * 64];
    gemm_body<2, 10, 0, 0>(ctx_bf, Wo, bo, out0, 1.0f, sA, sB, blockIdx.y, blockIdx.x);
}

// ---------------- attention: two-pass online softmax, no score LDS ---------
// 512 threads = 8 waves; LDS ~58 KB -> 2 blocks/CU (16 waves resident).
__global__ __launch_bounds__(512, 4)
void attn_kernel(const unsigned short* __restrict__ q_ws,
                 const unsigned short* __restrict__ k_ws,
                 const unsigned short* __restrict__ vT_ws,
                 const int* __restrict__ self_mask,
                 const int* __restrict__ ctx_mask,
                 const float* __restrict__ ctx_bias,
                 float* __restrict__ attn_out,
                 float* __restrict__ top_out,
                 unsigned short* __restrict__ ctx_ws)
{
    __shared__ unsigned short e_lds[16 * EPAD];   // 49,280 B (normalized P, bf16)
    __shared__ float s_part[16 * 64];             // 4,096 B (PV accum)
    __shared__ unsigned int mb[16 * 48];          // 3,072 B (mask bitmap)
    __shared__ float wred[16 * 8 * 3];            // 1,536 B
    __shared__ float fin[16 * 3];                 // 192 B  (mx, 1/sum, 1/ctx_sum)

    const int bid = blockIdx.x;
    const int bh  = bid & 31;        // same head -> same XCD slice
    const int qt  = bid >> 5;
    const int b   = bh >> 4;
    const int h   = bh & 15;
    const int t   = threadIdx.x;
    const int l   = t & 63;
    const int wid = t >> 6;          // 0..7, owns cols [wid*192, wid*192+192)
    const int lr  = l & 15;
    const int lg  = l >> 4;
    const int qrow0 = qt * 16;

    // ---- mask bitmap build + s_part zero ----
    {
        int row = t >> 5, w = t & 31;     // t < 512: all threads
        const int4* p = (const int4*)(self_mask + ((size_t)b * SL + qrow0 + row) * SL + w * 32);
        unsigned bits = 0;
        #pragma unroll
        for (int g = 0; g < 8; ++g) {
            int4 v = p[g];
            bits |= (unsigned)(v.x != 0) << (g * 4);
            bits |= (unsigned)(v.y != 0) << (g * 4 + 1);
            bits |= (unsigned)(v.z != 0) << (g * 4 + 2);
            bits |= (unsigned)(v.w != 0) << (g * 4 + 3);
        }
        mb[row * 48 + w] = bits;
    }
    if (t < 256) {
        int row = t >> 4, w = t & 15;
        const int4* p = (const int4*)(ctx_mask + (size_t)b * CL + w * 32);
        unsigned bits = 0;
        #pragma unroll
        for (int g = 0; g < 8; ++g) {
            int4 v = p[g];
            bits |= (unsigned)(v.x != 0) << (g * 4);
            bits |= (unsigned)(v.y != 0) << (g * 4 + 1);
            bits |= (unsigned)(v.z != 0) << (g * 4 + 2);
            bits |= (unsigned)(v.w != 0) << (g * 4 + 3);
        }
        mb[row * 48 + 32 + w] = bits;
    }
    s_part[t] = 0.f;
    s_part[t + 512] = 0.f;

    const unsigned short* qb = q_ws + ((size_t)bh * SL + qrow0) * D;
    const unsigned short* kb = k_ws + (size_t)bh * KL * D;
    const float cb = ctx_bias[0];
    bf16x8 aq0 = ld8(qb + lr * D + lg * 8);
    bf16x8 aq1 = ld8(qb + lr * D + 32 + lg * 8);
    __syncthreads();

    // ---- pass 1: QK^T + online (max, sum, ctx_sum); nothing stored ----
    float m[4], sa[4], sc[4];
    #pragma unroll
    for (int r = 0; r < 4; ++r) { m[r] = -3.0e38f; sa[r] = 0.f; sc[r] = 0.f; }

    for (int jj = 0; jj < 12; ++jj) {
        int j = wid * 12 + jj;
        int col = j * 16 + lr;
        bf16x8 bk0 = ld8(kb + (size_t)col * D + lg * 8);
        bf16x8 bk1 = ld8(kb + (size_t)col * D + 32 + lg * 8);
        f32x4 c = {};
        c = __builtin_amdgcn_mfma_f32_16x16x32_bf16(aq0, bk0, c, 0, 0, 0);
        c = __builtin_amdgcn_mfma_f32_16x16x32_bf16(aq1, bk1, c, 0, 0, 0);
        const int isctx = (col >= SL);
        const int wi = col >> 5, bit = col & 31;
        #pragma unroll
        for (int r = 0; r < 4; ++r) {
            int row = lg * 4 + r;
            float v = c[r] + (isctx ? cb : 0.f);
            if ((mb[row * 48 + wi] >> bit) & 1u) v = -1e30f;
            float nm = fmaxf(m[r], v);
            float rs = __expf(m[r] - nm);
            float ev = __expf(v - nm);
            sa[r] = sa[r] * rs + ev;
            sc[r] = sc[r] * rs + (isctx ? ev : 0.f);
            m[r]  = nm;
        }
    }
    // reduce across the 16 lanes sharing each row (xor bits 0..3)
    #pragma unroll
    for (int off = 1; off < 16; off <<= 1) {
        #pragma unroll
        for (int r = 0; r < 4; ++r) {
            float om = __shfl_xor(m[r], off);
            float os = __shfl_xor(sa[r], off);
            float oc = __shfl_xor(sc[r], off);
            float nm = fmaxf(m[r], om);
            float e1 = __expf(m[r] - nm), e2 = __expf(om - nm);
            sa[r] = sa[r] * e1 + os * e2;
            sc[r] = sc[r] * e1 + oc * e2;
            m[r]  = nm;
        }
    }
    if (lr == 0) {
        #pragma unroll
        for (int r = 0; r < 4; ++r) {
            int row = lg * 4 + r;
            wred[(row * 8 + wid) * 3 + 0] = m[r];
            wred[(row * 8 + wid) * 3 + 1] = sa[r];
            wred[(row * 8 + wid) * 3 + 2] = sc[r];
        }
    }
    __syncthreads();
    if (t < 16) {
        float fm = -3.0e38f, fs = 0.f, fc = 0.f;
        #pragma unroll
        for (int w = 0; w < 8; ++w) {
            float wm = wred[(t * 8 + w) * 3 + 0];
            float ws = wred[(t * 8 + w) * 3 + 1];
            float wc = wred[(t * 8 + w) * 3 + 2];
            float nm = fmaxf(fm, wm);
            float e1 = __expf(fm - nm), e2 = __expf(wm - nm);
            fs = fs * e1 + ws * e2;
            fc = fc * e1 + wc * e2;
            fm = nm;
        }
        fin[t * 3 + 0] = fm;
        fin[t * 3 + 1] = 1.0f / fs;
        fin[t * 3 + 2] = 1.0f / fc;
    }
    __syncthreads();

    // ---- pass 2: recompute, normalize, write attn (nt) + e_lds (bf16) ----
    float* aout = attn_out + ((size_t)bh * SL + qrow0) * KL;
    float* tout = top_out + ((size_t)b * SL + qrow0) * CL;
    for (int jj = 0; jj < 12; ++jj) {
        int j = wid * 12 + jj;
        int col = j * 16 + lr;
        bf16x8 bk0 = ld8(kb + (size_t)col * D + lg * 8);
        bf16x8 bk1 = ld8(kb + (size_t)col * D + 32 + lg * 8);
        f32x4 c = {};
        c = __builtin_amdgcn_mfma_f32_16x16x32_bf16(aq0, bk0, c, 0, 0, 0);
        c = __builtin_amdgcn_mfma_f32_16x16x32_bf16(aq1, bk1, c, 0, 0, 0);
        const int isctx = (col >= SL);
        const int wi = col >> 5, bit = col & 31;
        #pragma unroll
        for (int r = 0; r < 4; ++r) {
            int row = lg * 4 + r;
            float v = c[r] + (isctx ? cb : 0.f);
            if ((mb[row * 48 + wi] >> bit) & 1u) v = -1e30f;
            float ev = __expf(v - fin[row * 3 + 0]);
            float p  = ev * fin[row * 3 + 1];
            __builtin_nontemporal_store(p, aout + (size_t)row * KL + col);
            e_lds[row * EPAD + col] = (unsigned short)f2b(p);
            if (h == 0 && isctx) {
                float tp = ev * fin[row * 3 + 2];
                __builtin_nontemporal_store(tp, tout + (size_t)row * CL + (col - SL));
            }
        }
    }
    __syncthreads();

    // ---- PV on normalized bf16 P from e_lds ----
    const unsigned short* vb = vT_ws + (size_t)bh * D * KL;
    f32x4 accv[4] = {};
    for (int ks = 0; ks < 6; ++ks) {
        int k0 = wid * 192 + ks * 32;
        bf16x8 ap = ld8(e_lds + lr * EPAD + k0 + lg * 8);
        #pragma unroll
        for (int df = 0; df < 4; ++df) {
            bf16x8 bv = ld8(vb + (size_t)(df * 16 + lr) * KL + k0 + lg * 8);
            accv[df] = __builtin_amdgcn_mfma_f32_16x16x32_bf16(ap, bv, accv[df], 0, 0, 0);
        }
    }
    #pragma unroll
    for (int df = 0; df < 4; ++df)
        #pragma unroll
        for (int r = 0; r < 4; ++r)
            atomicAdd(&s_part[(lg * 4 + r) * 64 + df * 16 + lr], accv[df][r]);
    __syncthreads();

    for (int i = t; i < 1024; i += 512) {
        int srow = i >> 6, dd = i & 63;
        ctx_ws[((size_t)b * SL + qrow0 + srow) * DM + h * D + dd]
            = (unsigned short)f2b(s_part[i]);
    }
}

extern "C" void kernel_launch(void* const* d_in, const int* in_sizes, int n_in,
                              void* d_out, int out_size, void* d_ws, size_t ws_size,
                              hipStream_t stream)
{
    const float* self_kvq = (const float*)d_in[0];
    const float* ctx_kv   = (const float*)d_in[1];
    const int*   self_mask= (const int*)d_in[2];
    const int*   ctx_mask = (const int*)d_in[3];
    const float* Wq  = (const float*)d_in[4];
    const float* bq  = (const float*)d_in[5];
    const float* Wks = (const float*)d_in[6];
    const float* bks = (const float*)d_in[7];
    const float* Wvs = (const float*)d_in[8];
    const float* bvs = (const float*)d_in[9];
    const float* Wkc = (const float*)d_in[10];
    const float* bkc = (const float*)d_in[11];
    const float* Wvc = (const float*)d_in[12];
    const float* bvc = (const float*)d_in[13];
    const float* ctx_bias = (const float*)d_in[14];
    const float* Wo  = (const float*)d_in[15];
    const float* bo  = (const float*)d_in[16];

    float* out0     = (float*)d_out;                       // (B, SL, DM)
    float* out_top  = out0 + (size_t)B * SL * DM;          // (B, SL, CL)
    float* out_attn = out_top + (size_t)B * SL * CL;       // (B, H, SL, KL)

    unsigned short* wsp  = (unsigned short*)d_ws;
    unsigned short* Abf_self = wsp + 0 * M1;   // 2M (aliased by ctx_ws later)
    unsigned short* Abf_ctx  = wsp + 2 * M1;
    unsigned short* Wq_b     = wsp + 3 * M1;
    unsigned short* Wks_b    = wsp + 4 * M1;
    unsigned short* Wvs_b    = wsp + 5 * M1;
    unsigned short* Wkc_b    = wsp + 6 * M1;
    unsigned short* Wvc_b    = wsp + 7 * M1;
    unsigned short* Wo_b     = wsp + 8 * M1;
    unsigned short* q_ws     = wsp + 9 * M1;   // [B,H,SL,64]
    unsigned short* k_ws     = wsp + 11 * M1;  // [B,H,KL,64]
    unsigned short* vT_ws    = wsp + 14 * M1;  // [B,H,64,KL]
    unsigned short* ctx_ws   = wsp + 0;        // [B*SL, DM] (alias Abf_self)

    ConvSrc cs;
    cs.p[0] = self_kvq; cs.p[1] = ctx_kv;
    cs.p[2] = Wq; cs.p[3] = Wks; cs.p[4] = Wvs;
    cs.p[5] = Wkc; cs.p[6] = Wvc; cs.p[7] = Wo;
    convert_kernel<<<4608, 256, 0, stream>>>(cs, wsp);

    proj_kernel<<<dim3(1024), 256, 0, stream>>>(
        Abf_self, Abf_ctx, Wq_b, Wks_b, Wvs_b, Wkc_b, Wvc_b,
        bq, bks, bvs, bkc, bvc, q_ws, k_ws, vT_ws);

    attn_kernel<<<dim3(2048), 512, 0, stream>>>(q_ws, k_ws, vT_ws,
        self_mask, ctx_mask, ctx_bias, out_attn, out_top, ctx_ws);

    out_proj_kernel<<<dim3(8, 32), 256, 0, stream>>>(ctx_ws, Wo_b, bo, out0);
}

// Round 5
// 488.268 us; speedup vs baseline: 1.0792x; 1.0792x over previous
//
#include <hip/hip_runtime.h>
#include <cstdint>

constexpr int H  = 16;
constexpr int D  = 64;
constexpr int DM = 1024;
constexpr int B  = 2;
constexpr int SL = 1024;
constexpr int CL = 512;
constexpr int KL = SL + CL;   // 1536
constexpr int EPAD = 1544;    // bf16 e-row stride (shorts); 772 words % 32 = 4
constexpr size_t M1 = 1u << 20;

typedef short bf16x8  __attribute__((ext_vector_type(8)));
typedef float f32x4   __attribute__((ext_vector_type(4)));
typedef short short4v __attribute__((ext_vector_type(4)));

__device__ __forceinline__ short f2b(float f) {
    uint32_t u = __float_as_uint(f);
    u = (u + 0x7fffu + ((u >> 16) & 1u)) >> 16;   // RNE fp32 -> bf16
    return (short)u;
}

__device__ __forceinline__ bf16x8 ld8(const unsigned short* p) {
    return *reinterpret_cast<const bf16x8*>(p);
}

__device__ __forceinline__ void async16(const void* g, void* l) {
    __builtin_amdgcn_global_load_lds(
        (const __attribute__((address_space(1))) void*)g,
        (__attribute__((address_space(3))) void*)l,
        16, 0, 0);
}

// ---------------- fp32 -> bf16 bulk convert --------------------------------
struct ConvSrc { const float* p[8]; };

__global__ __launch_bounds__(256)
void convert_kernel(ConvSrc srcs, unsigned short* __restrict__ dst)
{
    size_t i8 = (size_t)blockIdx.x * 256 + threadIdx.x;
    size_t e  = i8 * 8;                                   // < 9M
    int u = (int)(e >> 20);
    const float* s; size_t off;
    if (u < 2) { s = srcs.p[0]; off = e; }
    else       { s = srcs.p[u - 1]; off = e - ((size_t)u << 20); }
    float4 a = *reinterpret_cast<const float4*>(s + off);
    float4 b = *reinterpret_cast<const float4*>(s + off + 4);
    bf16x8 r;
    r[0]=f2b(a.x); r[1]=f2b(a.y); r[2]=f2b(a.z); r[3]=f2b(a.w);
    r[4]=f2b(b.x); r[5]=f2b(b.y); r[6]=f2b(b.z); r[7]=f2b(b.w);
    *reinterpret_cast<bf16x8*>(dst + e) = r;
}

// ---------------- 64x128-tile, BK=64, swizzled-LDS bf16 GEMM ---------------
template<int MODE, int RPB_SHIFT, int OUTLEN, int ROWOFF>
__device__ __forceinline__ void gemm_body(
    const unsigned short* __restrict__ A,
    const unsigned short* __restrict__ W,
    const float* __restrict__ bias,
    void* __restrict__ outp, float scale,
    unsigned short* sA, unsigned short* sB, int by, int bx)
{
    const int t   = threadIdx.x;
    const int l   = t & 63;
    const int wid = t >> 6;
    const int lr  = l & 15, lg = l >> 4;
    const int mbase = by * 64;
    const int nbase = bx * 128;

    f32x4 acc[4][2] = {};
    for (int k0 = 0; k0 < DM; k0 += 64) {
        #pragma unroll
        for (int i = 0; i < 2; ++i) {
            int c = t + 256 * i;
            int row = c >> 3, gd = (c & 7) ^ (row & 7);
            async16(A + (size_t)(mbase + row) * DM + k0 + gd * 8, sA + c * 8);
        }
        #pragma unroll
        for (int i = 0; i < 4; ++i) {
            int c = t + 256 * i;
            int row = c >> 3, gd = (c & 7) ^ (row & 7);
            async16(W + (size_t)(nbase + row) * DM + k0 + gd * 8, sB + c * 8);
        }
        __syncthreads();
        bf16x8 af[4][2], bfr[2][2];
        #pragma unroll
        for (int s = 0; s < 2; ++s) {
            #pragma unroll
            for (int i = 0; i < 4; ++i) {
                int row = i * 16 + lr;
                af[i][s] = ld8(sA + (row * 8 + ((s * 4 + lg) ^ (row & 7))) * 8);
            }
            #pragma unroll
            for (int j = 0; j < 2; ++j) {
                int row = wid * 32 + j * 16 + lr;
                bfr[j][s] = ld8(sB + (row * 8 + ((s * 4 + lg) ^ (row & 7))) * 8);
            }
        }
        #pragma unroll
        for (int s = 0; s < 2; ++s)
            #pragma unroll
            for (int i = 0; i < 4; ++i)
                #pragma unroll
                for (int j = 0; j < 2; ++j)
                    acc[i][j] = __builtin_amdgcn_mfma_f32_16x16x32_bf16(af[i][s], bfr[j][s], acc[i][j], 0, 0, 0);
        __syncthreads();
    }

    #pragma unroll
    for (int mi = 0; mi < 4; ++mi) {
        #pragma unroll
        for (int nj = 0; nj < 2; ++nj) {
            int n = nbase + wid * 32 + nj * 16 + lr;     // C/D col = lane&15
            float bi = bias[n];
            if (MODE == 1) {
                int m0 = mbase + mi * 16 + lg * 4;
                int bb = m0 >> RPB_SHIFT;
                int s0 = m0 & ((1 << RPB_SHIFT) - 1);
                int hh = n >> 6, dd = n & 63;
                unsigned short* o = (unsigned short*)outp +
                    ((size_t)(bb * H + hh) * D + dd) * KL + ROWOFF + s0;
                short4v pk;
                #pragma unroll
                for (int r = 0; r < 4; ++r) pk[r] = f2b((acc[mi][nj][r] + bi) * scale);
                *reinterpret_cast<short4v*>(o) = pk;
            } else {
                #pragma unroll
                for (int r = 0; r < 4; ++r) {
                    int m = mbase + mi * 16 + lg * 4 + r;
                    float v = (acc[mi][nj][r] + bi) * scale;
                    if (MODE == 0) {
                        int bb = m >> RPB_SHIFT;
                        int s  = m & ((1 << RPB_SHIFT) - 1);
                        int hh = n >> 6, dd = n & 63;
                        ((unsigned short*)outp)[((size_t)(bb * H + hh) * OUTLEN + ROWOFF + s) * D + dd]
                            = (unsigned short)f2b(v);
                    } else {
                        __builtin_nontemporal_store(v, (float*)outp + (size_t)m * DM + n);
                    }
                }
            }
        }
    }
}

__global__ __launch_bounds__(256)
void proj_kernel(const unsigned short* __restrict__ Aself,
                 const unsigned short* __restrict__ Actx,
                 const unsigned short* __restrict__ Wq,
                 const unsigned short* __restrict__ Wks,
                 const unsigned short* __restrict__ Wvs,
                 const unsigned short* __restrict__ Wkc,
                 const unsigned short* __restrict__ Wvc,
                 const float* __restrict__ bq,  const float* __restrict__ bks,
                 const float* __restrict__ bvs, const float* __restrict__ bkc,
                 const float* __restrict__ bvc,
                 unsigned short* __restrict__ q_ws,
                 unsigned short* __restrict__ k_ws,
                 unsigned short* __restrict__ vT_ws)
{
    __shared__ unsigned short sA[64 * 64];    // 8 KB
    __shared__ unsigned short sB[128 * 64];   // 16 KB
    int bid = blockIdx.x;
    int z, by, bx;
    if (bid < 768) { z = bid >> 8; int r = bid & 255; by = r >> 3; bx = r & 7; }
    else { int tt = bid - 768; z = 3 + (tt >> 7); int r = tt & 127; by = r >> 3; bx = r & 7; }
    if (z == 0)
        gemm_body<0, 10, SL, 0 >(Aself, Wq,  bq,  q_ws,  0.125f, sA, sB, by, bx);
    else if (z == 1)
        gemm_body<0, 10, KL, 0 >(Aself, Wks, bks, k_ws,  1.0f,   sA, sB, by, bx);
    else if (z == 2)
        gemm_body<1, 10, 0,  0 >(Aself, Wvs, bvs, vT_ws, 1.0f,   sA, sB, by, bx);
    else if (z == 3)
        gemm_body<0, 9,  KL, SL>(Actx,  Wkc, bkc, k_ws,  1.0f,   sA, sB, by, bx);
    else
        gemm_body<1, 9,  0,  SL>(Actx,  Wvc, bvc, vT_ws, 1.0f,   sA, sB, by, bx);
}

__global__ __launch_bounds__(256)
void out_proj_kernel(const unsigned short* __restrict__ ctx_bf,
                     const unsigned short* __restrict__ Wo,
                     const float* __restrict__ bo,
                     float* __restrict__ out0)
{
    __shared__ unsigned short sA[64 * 64];
    __shared__ unsigned short sB[128 * 64];
    gemm_body<2, 10, 0, 0>(ctx_bf, Wo, bo, out0, 1.0f, sA, sB, blockIdx.y, blockIdx.x);
}

// ---------------- attention: single pass, scores in registers --------------
// 512 threads = 8 waves; LDS ~58 KB -> 2 blocks/CU (16 waves resident).
__global__ __launch_bounds__(512, 4)
void attn_kernel(const unsigned short* __restrict__ q_ws,
                 const unsigned short* __restrict__ k_ws,
                 const unsigned short* __restrict__ vT_ws,
                 const int* __restrict__ self_mask,
                 const int* __restrict__ ctx_mask,
                 const float* __restrict__ ctx_bias,
                 float* __restrict__ attn_out,
                 float* __restrict__ top_out,
                 unsigned short* __restrict__ ctx_ws)
{
    __shared__ unsigned short e_lds[16 * EPAD];   // 49,408 B (normalized P, bf16)
    __shared__ float s_part[16 * 64];             // 4,096 B (PV accum)
    __shared__ unsigned int mb[16 * 48];          // 3,072 B (mask bitmap)
    __shared__ float wredm[16 * 8];               // 512 B
    __shared__ float wreds[16 * 8];               // 512 B
    __shared__ float wredc[16 * 8];               // 512 B

    const int bid = blockIdx.x;
    const int bh  = bid & 31;        // bid%8 == bh%8 -> head pinned to one XCD
    const int qt  = bid >> 5;
    const int b   = bh >> 4;
    const int h   = bh & 15;
    const int t   = threadIdx.x;
    const int l   = t & 63;
    const int wid = t >> 6;          // wave owns cols [wid*192, wid*192+192)
    const int lr  = l & 15;
    const int lg  = l >> 4;
    const int qrow0 = qt * 16;

    // ---- mask bitmap build + s_part zero ----
    {
        int row = t >> 5, w = t & 31;
        const int4* p = (const int4*)(self_mask + ((size_t)b * SL + qrow0 + row) * SL + w * 32);
        unsigned bits = 0;
        #pragma unroll
        for (int g = 0; g < 8; ++g) {
            int4 v = p[g];
            bits |= (unsigned)(v.x != 0) << (g * 4);
            bits |= (unsigned)(v.y != 0) << (g * 4 + 1);
            bits |= (unsigned)(v.z != 0) << (g * 4 + 2);
            bits |= (unsigned)(v.w != 0) << (g * 4 + 3);
        }
        mb[row * 48 + w] = bits;
    }
    if (t < 256) {
        int row = t >> 4, w = t & 15;
        const int4* p = (const int4*)(ctx_mask + (size_t)b * CL + w * 32);
        unsigned bits = 0;
        #pragma unroll
        for (int g = 0; g < 8; ++g) {
            int4 v = p[g];
            bits |= (unsigned)(v.x != 0) << (g * 4);
            bits |= (unsigned)(v.y != 0) << (g * 4 + 1);
            bits |= (unsigned)(v.z != 0) << (g * 4 + 2);
            bits |= (unsigned)(v.w != 0) << (g * 4 + 3);
        }
        mb[row * 48 + 32 + w] = bits;
    }
    s_part[t] = 0.f;
    s_part[t + 512] = 0.f;

    const unsigned short* qb = q_ws + ((size_t)bh * SL + qrow0) * D;
    const unsigned short* kb = k_ws + (size_t)bh * KL * D;
    const float cb = ctx_bias[0];
    bf16x8 aq0 = ld8(qb + lr * D + lg * 8);
    bf16x8 aq1 = ld8(qb + lr * D + 32 + lg * 8);
    __syncthreads();

    // ---- QK^T: 12 fragments per wave, all kept in registers ----
    f32x4 c[12];
    float m[4] = {-3.0e38f, -3.0e38f, -3.0e38f, -3.0e38f};
    #pragma unroll
    for (int jj = 0; jj < 12; ++jj) {
        int j = wid * 12 + jj;
        int col = j * 16 + lr;
        bf16x8 bk0 = ld8(kb + (size_t)col * D + lg * 8);
        bf16x8 bk1 = ld8(kb + (size_t)col * D + 32 + lg * 8);
        f32x4 cc = {};
        cc = __builtin_amdgcn_mfma_f32_16x16x32_bf16(aq0, bk0, cc, 0, 0, 0);
        cc = __builtin_amdgcn_mfma_f32_16x16x32_bf16(aq1, bk1, cc, 0, 0, 0);
        const int isctx = (j >= 64);
        const int wi = j >> 1, bit = (j & 1) * 16 + lr;
        #pragma unroll
        for (int r = 0; r < 4; ++r) {
            int row = lg * 4 + r;
            float v = cc[r] + (isctx ? cb : 0.f);
            if ((mb[row * 48 + wi] >> bit) & 1u) v = -1e30f;
            cc[r] = v;
            m[r] = fmaxf(m[r], v);
        }
        c[jj] = cc;
    }

    // per-wave row max across the 16 lanes (lr) of each lane-group
    #pragma unroll
    for (int off = 1; off < 16; off <<= 1)
        #pragma unroll
        for (int r = 0; r < 4; ++r)
            m[r] = fmaxf(m[r], __shfl_xor(m[r], off));
    if (lr == 0) {
        #pragma unroll
        for (int r = 0; r < 4; ++r)
            wredm[(lg * 4 + r) * 8 + wid] = m[r];
    }
    __syncthreads();

    // global row max (broadcast LDS reads)
    float gm[4];
    #pragma unroll
    for (int r = 0; r < 4; ++r) {
        int row = lg * 4 + r;
        float v = wredm[row * 8 + 0];
        #pragma unroll
        for (int w = 1; w < 8; ++w) v = fmaxf(v, wredm[row * 8 + w]);
        gm[r] = v;
    }

    // exp in place + partial sums
    float sum[4] = {0.f, 0.f, 0.f, 0.f}, csum[4] = {0.f, 0.f, 0.f, 0.f};
    #pragma unroll
    for (int jj = 0; jj < 12; ++jj) {
        const int isctx = (wid * 12 + jj >= 64);
        #pragma unroll
        for (int r = 0; r < 4; ++r) {
            float e = __expf(c[jj][r] - gm[r]);
            c[jj][r] = e;
            sum[r] += e;
            if (isctx) csum[r] += e;
        }
    }
    #pragma unroll
    for (int off = 1; off < 16; off <<= 1)
        #pragma unroll
        for (int r = 0; r < 4; ++r) {
            sum[r]  += __shfl_xor(sum[r], off);
            csum[r] += __shfl_xor(csum[r], off);
        }
    if (lr == 0) {
        #pragma unroll
        for (int r = 0; r < 4; ++r) {
            wreds[(lg * 4 + r) * 8 + wid] = sum[r];
            wredc[(lg * 4 + r) * 8 + wid] = csum[r];
        }
    }
    __syncthreads();

    float rden[4], rcs[4];
    #pragma unroll
    for (int r = 0; r < 4; ++r) {
        int row = lg * 4 + r;
        float s = 0.f, cs = 0.f;
        #pragma unroll
        for (int w = 0; w < 8; ++w) { s += wreds[row * 8 + w]; cs += wredc[row * 8 + w]; }
        rden[r] = 1.0f / s;
        rcs[r]  = 1.0f / cs;
    }

    // ---- write attn (fp32, from regs) + e_lds (bf16) + top ----
    float* aout = attn_out + ((size_t)bh * SL + qrow0) * KL;
    float* tout = top_out + ((size_t)b * SL + qrow0) * CL;
    #pragma unroll
    for (int r = 0; r < 4; ++r) {
        int row = lg * 4 + r;
        float* arow = aout + (size_t)row * KL;
        #pragma unroll
        for (int jj = 0; jj < 12; ++jj) {
            int col = (wid * 12 + jj) * 16 + lr;
            float p = c[jj][r] * rden[r];
            arow[col] = p;
            e_lds[row * EPAD + col] = (unsigned short)f2b(p);
        }
    }
    if (h == 0) {
        #pragma unroll
        for (int r = 0; r < 4; ++r) {
            int row = lg * 4 + r;
            float* trow = tout + (size_t)row * CL;
            #pragma unroll
            for (int jj = 0; jj < 12; ++jj) {
                int j = wid * 12 + jj;
                if (j >= 64) trow[j * 16 + lr - SL] = c[jj][r] * rcs[r];
            }
        }
    }
    __syncthreads();

    // ---- PV on normalized bf16 P from e_lds ----
    const unsigned short* vb = vT_ws + (size_t)bh * D * KL;
    f32x4 accv[4] = {};
    for (int ks = 0; ks < 6; ++ks) {
        int k0 = wid * 192 + ks * 32;
        bf16x8 ap = ld8(e_lds + lr * EPAD + k0 + lg * 8);
        #pragma unroll
        for (int df = 0; df < 4; ++df) {
            bf16x8 bv = ld8(vb + (size_t)(df * 16 + lr) * KL + k0 + lg * 8);
            accv[df] = __builtin_amdgcn_mfma_f32_16x16x32_bf16(ap, bv, accv[df], 0, 0, 0);
        }
    }
    #pragma unroll
    for (int df = 0; df < 4; ++df)
        #pragma unroll
        for (int r = 0; r < 4; ++r)
            atomicAdd(&s_part[(lg * 4 + r) * 64 + df * 16 + lr], accv[df][r]);
    __syncthreads();

    for (int i = t; i < 1024; i += 512) {
        int srow = i >> 6, dd = i & 63;
        ctx_ws[((size_t)b * SL + qrow0 + srow) * DM + h * D + dd]
            = (unsigned short)f2b(s_part[i]);
    }
}

extern "C" void kernel_launch(void* const* d_in, const int* in_sizes, int n_in,
                              void* d_out, int out_size, void* d_ws, size_t ws_size,
                              hipStream_t stream)
{
    const float* self_kvq = (const float*)d_in[0];
    const float* ctx_kv   = (const float*)d_in[1];
    const int*   self_mask= (const int*)d_in[2];
    const int*   ctx_mask = (const int*)d_in[3];
    const float* Wq  = (const float*)d_in[4];
    const float* bq  = (const float*)d_in[5];
    const float* Wks = (const float*)d_in[6];
    const float* bks = (const float*)d_in[7];
    const float* Wvs = (const float*)d_in[8];
    const float* bvs = (const float*)d_in[9];
    const float* Wkc = (const float*)d_in[10];
    const float* bkc = (const float*)d_in[11];
    const float* Wvc = (const float*)d_in[12];
    const float* bvc = (const float*)d_in[13];
    const float* ctx_bias = (const float*)d_in[14];
    const float* Wo  = (const float*)d_in[15];
    const float* bo  = (const float*)d_in[16];

    float* out0     = (float*)d_out;                       // (B, SL, DM)
    float* out_top  = out0 + (size_t)B * SL * DM;          // (B, SL, CL)
    float* out_attn = out_top + (size_t)B * SL * CL;       // (B, H, SL, KL)

    unsigned short* wsp  = (unsigned short*)d_ws;
    unsigned short* Abf_self = wsp + 0 * M1;   // 2M (aliased by ctx_ws later)
    unsigned short* Abf_ctx  = wsp + 2 * M1;
    unsigned short* Wq_b     = wsp + 3 * M1;
    unsigned short* Wks_b    = wsp + 4 * M1;
    unsigned short* Wvs_b    = wsp + 5 * M1;
    unsigned short* Wkc_b    = wsp + 6 * M1;
    unsigned short* Wvc_b    = wsp + 7 * M1;
    unsigned short* Wo_b     = wsp + 8 * M1;
    unsigned short* q_ws     = wsp + 9 * M1;   // [B,H,SL,64]
    unsigned short* k_ws     = wsp + 11 * M1;  // [B,H,KL,64]
    unsigned short* vT_ws    = wsp + 14 * M1;  // [B,H,64,KL]
    unsigned short* ctx_ws   = wsp + 0;        // [B*SL, DM] (alias Abf_self)

    ConvSrc cs;
    cs.p[0] = self_kvq; cs.p[1] = ctx_kv;
    cs.p[2] = Wq; cs.p[3] = Wks; cs.p[4] = Wvs;
    cs.p[5] = Wkc; cs.p[6] = Wvc; cs.p[7] = Wo;
    convert_kernel<<<4608, 256, 0, stream>>>(cs, wsp);

    proj_kernel<<<dim3(1024), 256, 0, stream>>>(
        Abf_self, Abf_ctx, Wq_b, Wks_b, Wvs_b, Wkc_b, Wvc_b,
        bq, bks, bvs, bkc, bvc, q_ws, k_ws, vT_ws);

    attn_kernel<<<dim3(2048), 512, 0, stream>>>(q_ws, k_ws, vT_ws,
        self_mask, ctx_mask, ctx_bias, out_attn, out_top, ctx_ws);

    out_proj_kernel<<<dim3(8, 32), 256, 0, stream>>>(ctx_ws, Wo_b, bo, out0);
}